// Round 9
// baseline (223.969 us; speedup 1.0000x reference)
//
#include <hip/hip_runtime.h>
#include <math.h>

typedef float v2f __attribute__((ext_vector_type(2)));
#define FMA2(a, b, c) __builtin_elementwise_fma((a), (b), (c))

// ================= Kernel A: conv1+conv2+conv3+pool fused, one block per image =================
// R8: LDS-op diet. conv2 = 4 oc/thread on 128 threads; conv3 = 2 oc/thread on 128 threads with
// b64 row reads + b128 weight reads. Per-output FMA order identical to R7 (bitwise same result).
__global__ __launch_bounds__(256, 6)
void convpool_kernel(const float* __restrict__ x,
                     const float* __restrict__ w1, const float* __restrict__ b1,
                     const float* __restrict__ w2, const float* __restrict__ b2,
                     const float* __restrict__ w3, const float* __restrict__ b3,
                     float* __restrict__ poolout)
{
    __shared__ __align__(16) float arena[4620];   // conv1-out [4][33][35] -> conv3-in [8][18][18]
    __shared__ __align__(16) float w3p[1552];     // w3 padded [16][8][12] + b3[16] at 1536
    const int tid  = threadIdx.x;
    const int b    = blockIdx.x;
    const int lane = tid & 63;

    // ---- stage w3 into padded layout (k 0..8 of 12), b3; zero conv1-out halo ----
    for (int i = tid; i < 1152; i += 256) {
        int oc = i / 72, r = i - oc * 72;
        int ic = r / 9,  k = r - ic * 9;
        w3p[oc * 96 + ic * 12 + k] = w3[i];
    }
    if (tid < 16) w3p[1536 + tid] = b3[tid];
    for (int i = tid; i < 140; i += 256) { int oc = i / 35, c = i - oc * 35; arena[oc * 1155 + c] = 0.f; }
    for (int i = tid; i < 132; i += 256) { int oc = i / 33, r = i - oc * 33; arena[oc * 1155 + r * 35] = 0.f; }

    // ---- conv1: x from global, k5 s2 p2, 4 oc x (2+2) px per thread, packed ----
    {
        const float* xb = x + (size_t)b * 4096;
        const int oh  = tid >> 3;
        const int ow  = tid & 7;
        const int ow0 = ow * 4;
        const int c0  = ow0 * 2 - 2;
        const bool cmL = (ow == 0);
        const bool cmR = (ow == 7);
        v2f a01[4], a23[4];
        #pragma unroll
        for (int oc = 0; oc < 4; oc++) {
            const float bv = b1[oc];
            a01[oc] = (v2f){bv, bv};
            a23[oc] = (v2f){bv, bv};
        }
        #pragma unroll
        for (int kh = 0; kh < 5; kh++) {
            const int ih = oh * 2 - 2 + kh;
            if (ih >= 0 && ih < 64) {
                const float* row = xb + ih * 64;
                float colv[11];
                {
                    float v0 = row[cmL ? 0 : c0];
                    float v1 = row[cmL ? 0 : c0 + 1];
                    float vA = row[cmR ? 63 : c0 + 10];
                    colv[0]  = cmL ? 0.f : v0;
                    colv[1]  = cmL ? 0.f : v1;
                    colv[10] = cmR ? 0.f : vA;
                }
                #pragma unroll
                for (int cc = 2; cc < 10; cc++) colv[cc] = row[c0 + cc];
                #pragma unroll
                for (int kw = 0; kw < 5; kw++) {
                    const v2f c01 = {colv[kw],     colv[kw + 2]};
                    const v2f c23 = {colv[kw + 4], colv[kw + 6]};
                    #pragma unroll
                    for (int oc = 0; oc < 4; oc++) {
                        const float wv = w1[oc * 25 + kh * 5 + kw];
                        const v2f ws = {wv, wv};
                        a01[oc] = FMA2(c01, ws, a01[oc]);
                        a23[oc] = FMA2(c23, ws, a23[oc]);
                    }
                }
            }
        }
        #pragma unroll
        for (int oc = 0; oc < 4; oc++) {
            float* o = arena + oc * 1155 + (oh + 1) * 35 + ow0 + 1;
            o[0] = fmaxf(a01[oc].x, 0.f); o[1] = fmaxf(a01[oc].y, 0.f);
            o[2] = fmaxf(a23[oc].x, 0.f); o[3] = fmaxf(a23[oc].y, 0.f);
        }
    }
    __syncthreads();

    // ---- conv2: k3 s2 p1, 4 oc x (2+2) px per thread on 128 threads -> registers ----
    v2f c2acc[4][2];
    {
        if (tid < 128) {
            const int ocg = __builtin_amdgcn_readfirstlane(tid >> 6);   // 0 or 1, wave-uniform
            const int oh  = lane >> 2, ow0 = (lane & 3) * 4;
            #pragma unroll
            for (int i = 0; i < 4; i++) {
                const float bv = b2[ocg * 4 + i];
                c2acc[i][0] = (v2f){bv, bv};
                c2acc[i][1] = (v2f){bv, bv};
            }
            const int c0s = ow0 * 2;
            #pragma unroll
            for (int ic = 0; ic < 4; ic++) {
                const float* base = arena + ic * 1155;
                #pragma unroll
                for (int kh = 0; kh < 3; kh++) {
                    const int ihs = oh * 2 + kh;
                    float colv[9];
                    #pragma unroll
                    for (int cc = 0; cc < 9; cc++) colv[cc] = base[ihs * 35 + c0s + cc];
                    #pragma unroll
                    for (int kw = 0; kw < 3; kw++) {
                        const v2f c01 = {colv[kw],     colv[kw + 2]};
                        const v2f c23 = {colv[kw + 4], colv[kw + 6]};
                        #pragma unroll
                        for (int i = 0; i < 4; i++) {
                            const float wv = w2[((ocg * 4 + i) * 4 + ic) * 9 + kh * 3 + kw];
                            const v2f ws = {wv, wv};
                            c2acc[i][0] = FMA2(c01, ws, c2acc[i][0]);
                            c2acc[i][1] = FMA2(c23, ws, c2acc[i][1]);
                        }
                    }
                }
            }
        }
    }
    __syncthreads();

    // ---- conv2-out halo zero (256 threads) + store (128 threads) into [8][18][18] overlay ----
    for (int i = tid; i < 576; i += 256) {
        const int ch = i / 72, j = i - ch * 72;
        if (j < 18)      arena[ch * 324 + j] = 0.f;
        else if (j < 36) arena[ch * 324 + 17 * 18 + (j - 18)] = 0.f;
        else if (j < 52) arena[ch * 324 + (j - 35) * 18] = 0.f;
        else if (j < 68) arena[ch * 324 + (j - 51) * 18 + 17] = 0.f;
    }
    if (tid < 128) {
        const int ocg = tid >> 6;
        const int oh  = lane >> 2, ow0 = (lane & 3) * 4;
        #pragma unroll
        for (int i = 0; i < 4; i++) {
            float* o = arena + (ocg * 4 + i) * 324 + (oh + 1) * 18 + ow0 + 1;
            o[0] = fmaxf(c2acc[i][0].x, 0.f); o[1] = fmaxf(c2acc[i][0].y, 0.f);
            o[2] = fmaxf(c2acc[i][1].x, 0.f); o[3] = fmaxf(c2acc[i][1].y, 0.f);
        }
    }
    __syncthreads();

    // ---- conv3 + fused 8x8 avg pool: 2 oc x 4x4 tile per thread on 128 threads ----
    if (tid < 128) {
        const int op = tid >> 4;                 // 0..7 -> oc pair {2op, 2op+1}
        const int s  = tid & 15;
        const int tr = (s >> 2) * 4, tc = (s & 3) * 4;
        const int ocA = op * 2, ocB = ocA + 1;
        v2f accA[4][2], accB[4][2];
        {
            const float bvA = w3p[1536 + ocA], bvB = w3p[1536 + ocB];
            #pragma unroll
            for (int r = 0; r < 4; r++) {
                accA[r][0] = (v2f){bvA, bvA}; accA[r][1] = (v2f){bvA, bvA};
                accB[r][0] = (v2f){bvB, bvB}; accB[r][1] = (v2f){bvB, bvB};
            }
        }
        #pragma unroll
        for (int ic = 0; ic < 8; ic++) {
            const float* xc = arena + ic * 324;
            const float4 wA0 = *(const float4*)(w3p + ocA * 96 + ic * 12);
            const float4 wA1 = *(const float4*)(w3p + ocA * 96 + ic * 12 + 4);
            const float  wA8 = w3p[ocA * 96 + ic * 12 + 8];
            const float4 wB0 = *(const float4*)(w3p + ocB * 96 + ic * 12);
            const float4 wB1 = *(const float4*)(w3p + ocB * 96 + ic * 12 + 4);
            const float  wB8 = w3p[ocB * 96 + ic * 12 + 8];
            const float wA[9] = {wA0.x, wA0.y, wA0.z, wA0.w, wA1.x, wA1.y, wA1.z, wA1.w, wA8};
            const float wB[9] = {wB0.x, wB0.y, wB0.z, wB0.w, wB1.x, wB1.y, wB1.z, wB1.w, wB8};
            #pragma unroll
            for (int dr = 0; dr < 6; dr++) {
                const float2* rp = (const float2*)(xc + (tr + dr) * 18 + tc);   // even addr -> b64
                const float2 q0 = rp[0], q1 = rp[1], q2 = rp[2];
                const float prow[6] = {q0.x, q0.y, q1.x, q1.y, q2.x, q2.y};
                #pragma unroll
                for (int kh = 0; kh < 3; kh++) {
                    const int r = dr - kh;
                    if (r >= 0 && r < 4) {
                        #pragma unroll
                        for (int c2 = 0; c2 < 2; c2++) {
                            const int cb = c2 * 2;
                            v2f aA = accA[r][c2], aB = accB[r][c2];
                            #pragma unroll
                            for (int kw = 0; kw < 3; kw++) {
                                const v2f pp  = {prow[cb + kw], prow[cb + kw + 1]};
                                const v2f wAs = {wA[kh * 3 + kw], wA[kh * 3 + kw]};
                                const v2f wBs = {wB[kh * 3 + kw], wB[kh * 3 + kw]};
                                aA = FMA2(pp, wAs, aA);
                                aB = FMA2(pp, wBs, aB);
                            }
                            accA[r][c2] = aA; accB[r][c2] = aB;
                        }
                    }
                }
            }
        }
        // relu + tile sums (r asc, c asc order preserved), quadrant reduce via shfl
        float psA = 0.f, psB = 0.f;
        #pragma unroll
        for (int r = 0; r < 4; r++) {
            psA += fmaxf(accA[r][0].x, 0.f); psA += fmaxf(accA[r][0].y, 0.f);
            psA += fmaxf(accA[r][1].x, 0.f); psA += fmaxf(accA[r][1].y, 0.f);
            psB += fmaxf(accB[r][0].x, 0.f); psB += fmaxf(accB[r][0].y, 0.f);
            psB += fmaxf(accB[r][1].x, 0.f); psB += fmaxf(accB[r][1].y, 0.f);
        }
        psA += __shfl_xor(psA, 1, 64); psA += __shfl_xor(psA, 4, 64);
        psB += __shfl_xor(psB, 1, 64); psB += __shfl_xor(psB, 4, 64);
        if ((s & 5) == 0) {
            const int ii = s >> 3, jj = (s >> 1) & 1;
            poolout[b * 64 + ocA * 4 + ii * 2 + jj] = psA * (1.f / 64.f);
            poolout[b * 64 + ocB * 4 + ii * 2 + jj] = psB * (1.f / 64.f);
        }
    }
}

// ================= Kernel B: head, 4 elements per block, 1024 blocks =================
__global__ __launch_bounds__(256)
void head_kernel(const float* __restrict__ poolin,
                 const float* __restrict__ wf, const float* __restrict__ bf,
                 const float* __restrict__ qw,
                 const float* __restrict__ wc1, const float* __restrict__ bc1,
                 const float* __restrict__ wc2, const float* __restrict__ bc2,
                 const float* __restrict__ wc3, const float* __restrict__ bc3,
                 const float* __restrict__ wc4, const float* __restrict__ bc4,
                 const float* __restrict__ wc5, const float* __restrict__ bc5,
                 float* __restrict__ out)
{
    __shared__ __align__(16) float pool_s[256];
    __shared__ __align__(16) float feats[1024];
    __shared__ __align__(16) float h1[800];
    __shared__ __align__(16) float h2[600];
    __shared__ __align__(16) float h3[400];
    __shared__ __align__(16) float h4[200];
    __shared__ float zbuf[4];
    __shared__ float csc[56], css[56];

    const int tid  = threadIdx.x;
    const int blk  = blockIdx.x;
    const int lane = tid & 63;
    const int wv   = tid >> 6;

    pool_s[tid] = poolin[(size_t)blk * 256 + tid];
    if (tid < 56) {
        float th = qw[tid] * 0.5f;
        csc[tid] = cosf(th);
        css[tid] = sinf(th);
    }
    __syncthreads();

    {
        float acc[4];
        const float bv = bf[tid];
        #pragma unroll
        for (int e = 0; e < 4; e++) acc[e] = bv;
        const float4* wr = (const float4*)(wf + tid * 64);
        #pragma unroll
        for (int kc = 0; kc < 4; kc++) {
            float4 w0 = wr[kc * 4 + 0], w1_ = wr[kc * 4 + 1], w2_ = wr[kc * 4 + 2], w3_ = wr[kc * 4 + 3];
            #pragma unroll
            for (int e = 0; e < 4; e++) {
                const float4* pp = (const float4*)(pool_s + e * 64 + kc * 16);
                float4 p0 = pp[0], p1 = pp[1], p2 = pp[2], p3 = pp[3];
                float a = acc[e];
                a = fmaf(w0.x, p0.x, a); a = fmaf(w0.y, p0.y, a); a = fmaf(w0.z, p0.z, a); a = fmaf(w0.w, p0.w, a);
                a = fmaf(w1_.x, p1.x, a); a = fmaf(w1_.y, p1.y, a); a = fmaf(w1_.z, p1.z, a); a = fmaf(w1_.w, p1.w, a);
                a = fmaf(w2_.x, p2.x, a); a = fmaf(w2_.y, p2.y, a); a = fmaf(w2_.z, p2.z, a); a = fmaf(w2_.w, p2.w, a);
                a = fmaf(w3_.x, p3.x, a); a = fmaf(w3_.y, p3.y, a); a = fmaf(w3_.z, p3.z, a); a = fmaf(w3_.w, p3.w, a);
                acc[e] = a;
            }
        }
        #pragma unroll
        for (int e = 0; e < 4; e++) feats[e * 256 + tid] = fmaxf(acc[e], 0.f);
    }
    __syncthreads();

    {
        const float* base = feats + wv * 256;
        float v0 = base[lane], v1 = base[64 + lane];
        float v2 = base[128 + lane], v3 = base[192 + lane];
        float ssq = v0 * v0 + v1 * v1 + v2 * v2 + v3 * v3;
        #pragma unroll
        for (int off = 1; off < 64; off <<= 1) ssq += __shfl_xor(ssq, off, 64);
        const float inv = 1.0f / fmaxf(sqrtf(ssq), 1e-12f);
        v0 *= inv; v1 *= inv; v2 *= inv; v3 *= inv;

        for (int l = 0; l < 7; l++) {
            {
                float c = csc[l * 8 + 0], s = css[l * 8 + 0];
                float n0 = c * v0 - s * v2, n2 = s * v0 + c * v2;
                float n1 = c * v1 - s * v3, n3 = s * v1 + c * v3;
                float c1 = csc[l * 8 + 1], s1 = css[l * 8 + 1];
                v0 = c1 * n0 - s1 * n1; v1 = s1 * n0 + c1 * n1;
                v2 = c1 * n2 - s1 * n3; v3 = s1 * n2 + c1 * n3;
            }
            #pragma unroll
            for (int q = 2; q < 8; q++) {
                const int m = 1 << (7 - q);
                const float c = csc[l * 8 + q], s = css[l * 8 + q];
                const float sgn = (lane & m) ? s : -s;
                float t0 = __shfl_xor(v0, m, 64);
                float t1 = __shfl_xor(v1, m, 64);
                float t2 = __shfl_xor(v2, m, 64);
                float t3 = __shfl_xor(v3, m, 64);
                v0 = fmaf(sgn, t0, c * v0);
                v1 = fmaf(sgn, t1, c * v1);
                v2 = fmaf(sgn, t2, c * v2);
                v3 = fmaf(sgn, t3, c * v3);
            }
            { float t = v2; v2 = v3; v3 = t; }
            v1 = __shfl_xor(v1, 32, 64);
            v3 = __shfl_xor(v3, 32, 64);
            #pragma unroll
            for (int q = 2; q < 7; q++) {
                const int mc = 1 << (7 - q), mt = 1 << (6 - q);
                float t0 = __shfl_xor(v0, mt, 64);
                float t1 = __shfl_xor(v1, mt, 64);
                float t2 = __shfl_xor(v2, mt, 64);
                float t3 = __shfl_xor(v3, mt, 64);
                if (lane & mc) { v0 = t0; v1 = t1; v2 = t2; v3 = t3; }
            }
        }
        float m0 = v0 * v0 + v1 * v1 - v2 * v2 - v3 * v3;
        #pragma unroll
        for (int off = 1; off < 64; off <<= 1) m0 += __shfl_xor(m0, off, 64);
        if (lane == 0) zbuf[wv] = m0;
    }
    __syncthreads();

    if (tid < 200) {
        const float w = wc1[tid], bv = bc1[tid];
        #pragma unroll
        for (int e = 0; e < 4; e++) h1[e * 200 + tid] = fmaxf(fmaf(zbuf[e], w, bv), 0.f);
    }
    __syncthreads();
    if (tid < 150) {
        float acc[4];
        const float bv = bc2[tid];
        #pragma unroll
        for (int e = 0; e < 4; e++) acc[e] = bv;
        const float4* wr = (const float4*)(wc2 + tid * 200);
        for (int kc = 0; kc < 25; kc++) {
            float4 wa = wr[2 * kc], wb = wr[2 * kc + 1];
            #pragma unroll
            for (int e = 0; e < 4; e++) {
                const float4* hp = (const float4*)(h1 + e * 200) + 2 * kc;
                float4 ha = hp[0], hb = hp[1];
                float a = acc[e];
                a = fmaf(wa.x, ha.x, a); a = fmaf(wa.y, ha.y, a); a = fmaf(wa.z, ha.z, a); a = fmaf(wa.w, ha.w, a);
                a = fmaf(wb.x, hb.x, a); a = fmaf(wb.y, hb.y, a); a = fmaf(wb.z, hb.z, a); a = fmaf(wb.w, hb.w, a);
                acc[e] = a;
            }
        }
        #pragma unroll
        for (int e = 0; e < 4; e++) h2[e * 150 + tid] = fmaxf(acc[e], 0.f);
    }
    __syncthreads();
    if (tid < 100) {
        float acc[4];
        const float bv = bc3[tid];
        #pragma unroll
        for (int e = 0; e < 4; e++) acc[e] = bv;
        const float2* wr = (const float2*)(wc3 + tid * 150);
        for (int k = 0; k < 75; k++) {
            float2 wa = wr[k];
            #pragma unroll
            for (int e = 0; e < 4; e++) {
                float2 hv = ((const float2*)(h2 + e * 150))[k];
                acc[e] = fmaf(wa.x, hv.x, fmaf(wa.y, hv.y, acc[e]));
            }
        }
        #pragma unroll
        for (int e = 0; e < 4; e++) h3[e * 100 + tid] = fmaxf(acc[e], 0.f);
    }
    __syncthreads();
    if (tid < 50) {
        float acc[4];
        const float bv = bc4[tid];
        #pragma unroll
        for (int e = 0; e < 4; e++) acc[e] = bv;
        const float4* wr = (const float4*)(wc4 + tid * 100);
        for (int kc = 0; kc < 25; kc++) {
            float4 wa = wr[kc];
            #pragma unroll
            for (int e = 0; e < 4; e++) {
                float4 hv = ((const float4*)(h3 + e * 100))[kc];
                float a = acc[e];
                a = fmaf(wa.x, hv.x, a); a = fmaf(wa.y, hv.y, a);
                a = fmaf(wa.z, hv.z, a); a = fmaf(wa.w, hv.w, a);
                acc[e] = a;
            }
        }
        #pragma unroll
        for (int e = 0; e < 4; e++) h4[e * 50 + tid] = fmaxf(acc[e], 0.f);
    }
    __syncthreads();
    if (tid < 4) {
        float acc = bc5[0];
        const float2* wr = (const float2*)wc5;
        #pragma unroll
        for (int k = 0; k < 25; k++) {
            float2 wa = wr[k];
            float2 hv = ((const float2*)(h4 + tid * 50))[k];
            acc = fmaf(wa.x, hv.x, fmaf(wa.y, hv.y, acc));
        }
        out[blk * 4 + tid] = 1.0f / (1.0f + expf(-acc));
    }
}

extern "C" void kernel_launch(void* const* d_in, const int* in_sizes, int n_in,
                              void* d_out, int out_size, void* d_ws, size_t ws_size,
                              hipStream_t stream) {
    const float* x   = (const float*)d_in[0];
    const float* w1  = (const float*)d_in[1];
    const float* b1  = (const float*)d_in[2];
    const float* w2  = (const float*)d_in[3];
    const float* b2  = (const float*)d_in[4];
    const float* w3  = (const float*)d_in[5];
    const float* b3  = (const float*)d_in[6];
    const float* wf  = (const float*)d_in[7];
    const float* bf  = (const float*)d_in[8];
    const float* qw  = (const float*)d_in[9];
    const float* wc1 = (const float*)d_in[10];
    const float* bc1 = (const float*)d_in[11];
    const float* wc2 = (const float*)d_in[12];
    const float* bc2 = (const float*)d_in[13];
    const float* wc3 = (const float*)d_in[14];
    const float* bc3 = (const float*)d_in[15];
    const float* wc4 = (const float*)d_in[16];
    const float* bc4 = (const float*)d_in[17];
    const float* wc5 = (const float*)d_in[18];
    const float* bc5 = (const float*)d_in[19];
    float* out = (float*)d_out;

    float* poolbuf = (float*)d_ws;   // 4096*64 floats = 1 MB

    convpool_kernel<<<4096, 256, 0, stream>>>(x, w1, b1, w2, b2, w3, b3, poolbuf);
    head_kernel<<<1024, 256, 0, stream>>>(poolbuf, wf, bf, qw,
                                          wc1, bc1, wc2, bc2, wc3, bc3,
                                          wc4, bc4, wc5, bc5, out);
}

// Round 10
// 216.365 us; speedup vs baseline: 1.0351x; 1.0351x over previous
//
#include <hip/hip_runtime.h>
#include <math.h>

typedef float v2f __attribute__((ext_vector_type(2)));
#define FMA2(a, b, c) __builtin_elementwise_fma((a), (b), (c))

// ================= Kernel A: conv1+conv2+conv3+pool fused, one block per image =================
// R10: all 256 threads active in every phase (R7 mapping) + vectorized loads:
//  conv1 global taps via 2x dwordx4; conv1-out [4][33][36] -> conv2 reads 2xb128+b32;
//  conv2-out [8][18][20] -> conv3 reads b128+b64 per row, weights b128 from padded [16][8][12].
// Per-output FMA order identical to R7 (bitwise same result).
__global__ __launch_bounds__(256, 6)
void convpool_kernel(const float* __restrict__ x,
                     const float* __restrict__ w1, const float* __restrict__ b1,
                     const float* __restrict__ w2, const float* __restrict__ b2,
                     const float* __restrict__ w3, const float* __restrict__ b3,
                     float* __restrict__ poolout)
{
    __shared__ __align__(16) float arena[4752];   // conv1-out [4][33][36] -> conv3-in [8][18][20]
    __shared__ __align__(16) float w3p[1552];     // w3 padded [16][8][12] + b3[16] at 1536
    const int tid  = threadIdx.x;
    const int b    = blockIdx.x;
    const int lane = tid & 63;

    // ---- stage w3 into padded layout; b3; zero conv1-out halo (row0 + col0 per oc) ----
    for (int i = tid; i < 1152; i += 256) {
        int oc = i / 72, r = i - oc * 72;
        int ic = r / 9,  k = r - ic * 9;
        w3p[oc * 96 + ic * 12 + k] = w3[i];
    }
    if (tid < 16) w3p[1536 + tid] = b3[tid];
    for (int i = tid; i < 144; i += 256) { int oc = i / 36, c = i - oc * 36; arena[oc * 1188 + c] = 0.f; }
    for (int i = tid; i < 132; i += 256) { int oc = i / 33, r = i - oc * 33; arena[oc * 1188 + r * 36] = 0.f; }

    // ---- conv1: x from global, k5 s2 p2, 4 oc x (2+2) px per thread, packed ----
    {
        const float* xb = x + (size_t)b * 4096;
        const int oh  = tid >> 3;
        const int ow  = tid & 7;
        const int ow0 = ow * 4;
        const int c0  = ow0 * 2 - 2;
        const bool cmL = (ow == 0);
        const bool cmR = (ow == 7);
        v2f a01[4], a23[4];
        #pragma unroll
        for (int oc = 0; oc < 4; oc++) {
            const float bv = b1[oc];
            a01[oc] = (v2f){bv, bv};
            a23[oc] = (v2f){bv, bv};
        }
        #pragma unroll
        for (int kh = 0; kh < 5; kh++) {
            const int ih = oh * 2 - 2 + kh;
            if (ih >= 0 && ih < 64) {
                const float* row = xb + ih * 64;
                float colv[11];
                {   // edges: clamped addresses, masked values
                    float v0 = row[cmL ? 0 : c0];
                    float v1 = row[cmL ? 0 : c0 + 1];
                    float vA = row[cmR ? 63 : c0 + 10];
                    colv[0]  = cmL ? 0.f : v0;
                    colv[1]  = cmL ? 0.f : v1;
                    colv[10] = cmR ? 0.f : vA;
                }
                {   // middle 8 taps: two aligned dwordx4 (c0+2 = ow*8)
                    const float4 m0 = *(const float4*)(row + c0 + 2);
                    const float4 m1 = *(const float4*)(row + c0 + 6);
                    colv[2] = m0.x; colv[3] = m0.y; colv[4] = m0.z; colv[5] = m0.w;
                    colv[6] = m1.x; colv[7] = m1.y; colv[8] = m1.z; colv[9] = m1.w;
                }
                #pragma unroll
                for (int kw = 0; kw < 5; kw++) {
                    const v2f c01 = {colv[kw],     colv[kw + 2]};
                    const v2f c23 = {colv[kw + 4], colv[kw + 6]};
                    #pragma unroll
                    for (int oc = 0; oc < 4; oc++) {
                        const float wv = w1[oc * 25 + kh * 5 + kw];
                        const v2f ws = {wv, wv};
                        a01[oc] = FMA2(c01, ws, a01[oc]);
                        a23[oc] = FMA2(c23, ws, a23[oc]);
                    }
                }
            }
        }
        #pragma unroll
        for (int oc = 0; oc < 4; oc++) {
            float* o = arena + oc * 1188 + (oh + 1) * 36 + ow0 + 1;
            o[0] = fmaxf(a01[oc].x, 0.f); o[1] = fmaxf(a01[oc].y, 0.f);
            o[2] = fmaxf(a23[oc].x, 0.f); o[3] = fmaxf(a23[oc].y, 0.f);
        }
    }
    __syncthreads();

    // ---- conv2: k3 s2 p1, 2 oc x (2+2) px per thread on 256 threads -> registers ----
    v2f rA01, rA23, rB01, rB23;
    {
        const int oc0 = __builtin_amdgcn_readfirstlane(tid >> 6);   // 0..3, wave-uniform
        const int oh  = lane >> 2, ow0 = (lane & 3) * 4;
        {
            const float ba = b2[oc0], bb = b2[oc0 + 4];
            rA01 = (v2f){ba, ba}; rA23 = (v2f){ba, ba};
            rB01 = (v2f){bb, bb}; rB23 = (v2f){bb, bb};
        }
        const int c0s = ow0 * 2;                 // {0,8,16,24}: 16B-aligned with stride 36
        #pragma unroll
        for (int ic = 0; ic < 4; ic++) {
            const float* base = arena + ic * 1188;
            #pragma unroll
            for (int kh = 0; kh < 3; kh++) {
                const int ihs = oh * 2 + kh;     // stored row, [0,32]
                const float* rp = base + ihs * 36 + c0s;
                const float4 q0 = *(const float4*)(rp);      // colv[0..3]
                const float4 q1 = *(const float4*)(rp + 4);  // colv[4..7]
                const float  q8 = rp[8];                     // colv[8]
                const float colv[9] = {q0.x, q0.y, q0.z, q0.w, q1.x, q1.y, q1.z, q1.w, q8};
                #pragma unroll
                for (int kw = 0; kw < 3; kw++) {
                    const v2f c01 = {colv[kw],     colv[kw + 2]};
                    const v2f c23 = {colv[kw + 4], colv[kw + 6]};
                    const float wa = w2[((oc0    ) * 4 + ic) * 9 + kh * 3 + kw];
                    const float wb = w2[((oc0 + 4) * 4 + ic) * 9 + kh * 3 + kw];
                    const v2f was = {wa, wa}, wbs = {wb, wb};
                    rA01 = FMA2(c01, was, rA01);
                    rA23 = FMA2(c23, was, rA23);
                    rB01 = FMA2(c01, wbs, rB01);
                    rB23 = FMA2(c23, wbs, rB23);
                }
            }
        }
    }
    __syncthreads();

    // ---- conv2-out halo zero + store into [8][18][20] overlay ----
    for (int i = tid; i < 544; i += 256) {
        const int ch = i / 68, j = i - ch * 68;
        if (j < 18)      arena[ch * 360 + j] = 0.f;                   // row 0
        else if (j < 36) arena[ch * 360 + 17 * 20 + (j - 18)] = 0.f;  // row 17
        else if (j < 52) arena[ch * 360 + (j - 35) * 20] = 0.f;       // col 0, rows 1..16
        else             arena[ch * 360 + (j - 51) * 20 + 17] = 0.f;  // col 17, rows 1..16
    }
    {
        const int oc0 = __builtin_amdgcn_readfirstlane(tid >> 6);
        const int oh  = lane >> 2, ow0 = (lane & 3) * 4;
        float* oA = arena + oc0 * 360       + (oh + 1) * 20 + ow0 + 1;
        float* oB = arena + (oc0 + 4) * 360 + (oh + 1) * 20 + ow0 + 1;
        oA[0] = fmaxf(rA01.x, 0.f); oA[1] = fmaxf(rA01.y, 0.f);
        oA[2] = fmaxf(rA23.x, 0.f); oA[3] = fmaxf(rA23.y, 0.f);
        oB[0] = fmaxf(rB01.x, 0.f); oB[1] = fmaxf(rB01.y, 0.f);
        oB[2] = fmaxf(rB23.x, 0.f); oB[3] = fmaxf(rB23.y, 0.f);
    }
    __syncthreads();

    // ---- conv3 + fused 8x8 avg pool: thread = (oc, 4x4 tile), 256 threads ----
    {
        const int oc = tid >> 4, s = tid & 15;
        const int tr = (s >> 2) * 4, tc = (s & 3) * 4;
        v2f acc2[4][2];
        const float bv = w3p[1536 + oc];
        #pragma unroll
        for (int r = 0; r < 4; r++) {
            acc2[r][0] = (v2f){bv, bv};
            acc2[r][1] = (v2f){bv, bv};
        }
        #pragma unroll
        for (int ic = 0; ic < 8; ic++) {
            const float* xc = arena + ic * 360;
            const float4 wv0 = *(const float4*)(w3p + oc * 96 + ic * 12);
            const float4 wv1 = *(const float4*)(w3p + oc * 96 + ic * 12 + 4);
            const float  wv8 = w3p[oc * 96 + ic * 12 + 8];
            const float wv[9] = {wv0.x, wv0.y, wv0.z, wv0.w, wv1.x, wv1.y, wv1.z, wv1.w, wv8};
            float p[6][6];
            #pragma unroll
            for (int dr = 0; dr < 6; dr++) {
                const float* rp = xc + (tr + dr) * 20 + tc;   // 16B-aligned (stride 20, tc mult of 4)
                const float4 qa = *(const float4*)(rp);
                const float2 qb = *(const float2*)(rp + 4);
                p[dr][0] = qa.x; p[dr][1] = qa.y; p[dr][2] = qa.z;
                p[dr][3] = qa.w; p[dr][4] = qb.x; p[dr][5] = qb.y;
            }
            #pragma unroll
            for (int r = 0; r < 4; r++) {
                #pragma unroll
                for (int c2 = 0; c2 < 2; c2++) {
                    const int cb = c2 * 2;
                    v2f a = acc2[r][c2];
                    #pragma unroll
                    for (int kh = 0; kh < 3; kh++) {
                        #pragma unroll
                        for (int kw = 0; kw < 3; kw++) {
                            const v2f pp = {p[r + kh][cb + kw], p[r + kh][cb + kw + 1]};
                            const v2f ws = {wv[kh * 3 + kw], wv[kh * 3 + kw]};
                            a = FMA2(pp, ws, a);
                        }
                    }
                    acc2[r][c2] = a;
                }
            }
        }
        // relu + tile sum (r asc, c asc), quadrant reduce via shfl
        float ps = 0.f;
        #pragma unroll
        for (int r = 0; r < 4; r++) {
            ps += fmaxf(acc2[r][0].x, 0.f);
            ps += fmaxf(acc2[r][0].y, 0.f);
            ps += fmaxf(acc2[r][1].x, 0.f);
            ps += fmaxf(acc2[r][1].y, 0.f);
        }
        ps += __shfl_xor(ps, 1, 64);
        ps += __shfl_xor(ps, 4, 64);
        if ((s & 5) == 0) {
            const int ii = s >> 3, jj = (s >> 1) & 1;
            poolout[b * 64 + oc * 4 + ii * 2 + jj] = ps * (1.f / 64.f);
        }
    }
}

// ================= Kernel B: head, 4 elements per block, 1024 blocks =================
__global__ __launch_bounds__(256)
void head_kernel(const float* __restrict__ poolin,
                 const float* __restrict__ wf, const float* __restrict__ bf,
                 const float* __restrict__ qw,
                 const float* __restrict__ wc1, const float* __restrict__ bc1,
                 const float* __restrict__ wc2, const float* __restrict__ bc2,
                 const float* __restrict__ wc3, const float* __restrict__ bc3,
                 const float* __restrict__ wc4, const float* __restrict__ bc4,
                 const float* __restrict__ wc5, const float* __restrict__ bc5,
                 float* __restrict__ out)
{
    __shared__ __align__(16) float pool_s[256];
    __shared__ __align__(16) float feats[1024];
    __shared__ __align__(16) float h1[800];
    __shared__ __align__(16) float h2[600];
    __shared__ __align__(16) float h3[400];
    __shared__ __align__(16) float h4[200];
    __shared__ float zbuf[4];
    __shared__ float csc[56], css[56];

    const int tid  = threadIdx.x;
    const int blk  = blockIdx.x;
    const int lane = tid & 63;
    const int wv   = tid >> 6;

    pool_s[tid] = poolin[(size_t)blk * 256 + tid];
    if (tid < 56) {
        float th = qw[tid] * 0.5f;
        csc[tid] = cosf(th);
        css[tid] = sinf(th);
    }
    __syncthreads();

    {
        float acc[4];
        const float bv = bf[tid];
        #pragma unroll
        for (int e = 0; e < 4; e++) acc[e] = bv;
        const float4* wr = (const float4*)(wf + tid * 64);
        #pragma unroll
        for (int kc = 0; kc < 4; kc++) {
            float4 w0 = wr[kc * 4 + 0], w1_ = wr[kc * 4 + 1], w2_ = wr[kc * 4 + 2], w3_ = wr[kc * 4 + 3];
            #pragma unroll
            for (int e = 0; e < 4; e++) {
                const float4* pp = (const float4*)(pool_s + e * 64 + kc * 16);
                float4 p0 = pp[0], p1 = pp[1], p2 = pp[2], p3 = pp[3];
                float a = acc[e];
                a = fmaf(w0.x, p0.x, a); a = fmaf(w0.y, p0.y, a); a = fmaf(w0.z, p0.z, a); a = fmaf(w0.w, p0.w, a);
                a = fmaf(w1_.x, p1.x, a); a = fmaf(w1_.y, p1.y, a); a = fmaf(w1_.z, p1.z, a); a = fmaf(w1_.w, p1.w, a);
                a = fmaf(w2_.x, p2.x, a); a = fmaf(w2_.y, p2.y, a); a = fmaf(w2_.z, p2.z, a); a = fmaf(w2_.w, p2.w, a);
                a = fmaf(w3_.x, p3.x, a); a = fmaf(w3_.y, p3.y, a); a = fmaf(w3_.z, p3.z, a); a = fmaf(w3_.w, p3.w, a);
                acc[e] = a;
            }
        }
        #pragma unroll
        for (int e = 0; e < 4; e++) feats[e * 256 + tid] = fmaxf(acc[e], 0.f);
    }
    __syncthreads();

    {
        const float* base = feats + wv * 256;
        float v0 = base[lane], v1 = base[64 + lane];
        float v2 = base[128 + lane], v3 = base[192 + lane];
        float ssq = v0 * v0 + v1 * v1 + v2 * v2 + v3 * v3;
        #pragma unroll
        for (int off = 1; off < 64; off <<= 1) ssq += __shfl_xor(ssq, off, 64);
        const float inv = 1.0f / fmaxf(sqrtf(ssq), 1e-12f);
        v0 *= inv; v1 *= inv; v2 *= inv; v3 *= inv;

        for (int l = 0; l < 7; l++) {
            {
                float c = csc[l * 8 + 0], s = css[l * 8 + 0];
                float n0 = c * v0 - s * v2, n2 = s * v0 + c * v2;
                float n1 = c * v1 - s * v3, n3 = s * v1 + c * v3;
                float c1 = csc[l * 8 + 1], s1 = css[l * 8 + 1];
                v0 = c1 * n0 - s1 * n1; v1 = s1 * n0 + c1 * n1;
                v2 = c1 * n2 - s1 * n3; v3 = s1 * n2 + c1 * n3;
            }
            #pragma unroll
            for (int q = 2; q < 8; q++) {
                const int m = 1 << (7 - q);
                const float c = csc[l * 8 + q], s = css[l * 8 + q];
                const float sgn = (lane & m) ? s : -s;
                float t0 = __shfl_xor(v0, m, 64);
                float t1 = __shfl_xor(v1, m, 64);
                float t2 = __shfl_xor(v2, m, 64);
                float t3 = __shfl_xor(v3, m, 64);
                v0 = fmaf(sgn, t0, c * v0);
                v1 = fmaf(sgn, t1, c * v1);
                v2 = fmaf(sgn, t2, c * v2);
                v3 = fmaf(sgn, t3, c * v3);
            }
            { float t = v2; v2 = v3; v3 = t; }
            v1 = __shfl_xor(v1, 32, 64);
            v3 = __shfl_xor(v3, 32, 64);
            #pragma unroll
            for (int q = 2; q < 7; q++) {
                const int mc = 1 << (7 - q), mt = 1 << (6 - q);
                float t0 = __shfl_xor(v0, mt, 64);
                float t1 = __shfl_xor(v1, mt, 64);
                float t2 = __shfl_xor(v2, mt, 64);
                float t3 = __shfl_xor(v3, mt, 64);
                if (lane & mc) { v0 = t0; v1 = t1; v2 = t2; v3 = t3; }
            }
        }
        float m0 = v0 * v0 + v1 * v1 - v2 * v2 - v3 * v3;
        #pragma unroll
        for (int off = 1; off < 64; off <<= 1) m0 += __shfl_xor(m0, off, 64);
        if (lane == 0) zbuf[wv] = m0;
    }
    __syncthreads();

    if (tid < 200) {
        const float w = wc1[tid], bv = bc1[tid];
        #pragma unroll
        for (int e = 0; e < 4; e++) h1[e * 200 + tid] = fmaxf(fmaf(zbuf[e], w, bv), 0.f);
    }
    __syncthreads();
    if (tid < 150) {
        float acc[4];
        const float bv = bc2[tid];
        #pragma unroll
        for (int e = 0; e < 4; e++) acc[e] = bv;
        const float4* wr = (const float4*)(wc2 + tid * 200);
        for (int kc = 0; kc < 25; kc++) {
            float4 wa = wr[2 * kc], wb = wr[2 * kc + 1];
            #pragma unroll
            for (int e = 0; e < 4; e++) {
                const float4* hp = (const float4*)(h1 + e * 200) + 2 * kc;
                float4 ha = hp[0], hb = hp[1];
                float a = acc[e];
                a = fmaf(wa.x, ha.x, a); a = fmaf(wa.y, ha.y, a); a = fmaf(wa.z, ha.z, a); a = fmaf(wa.w, ha.w, a);
                a = fmaf(wb.x, hb.x, a); a = fmaf(wb.y, hb.y, a); a = fmaf(wb.z, hb.z, a); a = fmaf(wb.w, hb.w, a);
                acc[e] = a;
            }
        }
        #pragma unroll
        for (int e = 0; e < 4; e++) h2[e * 150 + tid] = fmaxf(acc[e], 0.f);
    }
    __syncthreads();
    if (tid < 100) {
        float acc[4];
        const float bv = bc3[tid];
        #pragma unroll
        for (int e = 0; e < 4; e++) acc[e] = bv;
        const float2* wr = (const float2*)(wc3 + tid * 150);
        for (int k = 0; k < 75; k++) {
            float2 wa = wr[k];
            #pragma unroll
            for (int e = 0; e < 4; e++) {
                float2 hv = ((const float2*)(h2 + e * 150))[k];
                acc[e] = fmaf(wa.x, hv.x, fmaf(wa.y, hv.y, acc[e]));
            }
        }
        #pragma unroll
        for (int e = 0; e < 4; e++) h3[e * 100 + tid] = fmaxf(acc[e], 0.f);
    }
    __syncthreads();
    if (tid < 50) {
        float acc[4];
        const float bv = bc4[tid];
        #pragma unroll
        for (int e = 0; e < 4; e++) acc[e] = bv;
        const float4* wr = (const float4*)(wc4 + tid * 100);
        for (int kc = 0; kc < 25; kc++) {
            float4 wa = wr[kc];
            #pragma unroll
            for (int e = 0; e < 4; e++) {
                float4 hv = ((const float4*)(h3 + e * 100))[kc];
                float a = acc[e];
                a = fmaf(wa.x, hv.x, a); a = fmaf(wa.y, hv.y, a);
                a = fmaf(wa.z, hv.z, a); a = fmaf(wa.w, hv.w, a);
                acc[e] = a;
            }
        }
        #pragma unroll
        for (int e = 0; e < 4; e++) h4[e * 50 + tid] = fmaxf(acc[e], 0.f);
    }
    __syncthreads();
    if (tid < 4) {
        float acc = bc5[0];
        const float2* wr = (const float2*)wc5;
        #pragma unroll
        for (int k = 0; k < 25; k++) {
            float2 wa = wr[k];
            float2 hv = ((const float2*)(h4 + tid * 50))[k];
            acc = fmaf(wa.x, hv.x, fmaf(wa.y, hv.y, acc));
        }
        out[blk * 4 + tid] = 1.0f / (1.0f + expf(-acc));
    }
}

extern "C" void kernel_launch(void* const* d_in, const int* in_sizes, int n_in,
                              void* d_out, int out_size, void* d_ws, size_t ws_size,
                              hipStream_t stream) {
    const float* x   = (const float*)d_in[0];
    const float* w1  = (const float*)d_in[1];
    const float* b1  = (const float*)d_in[2];
    const float* w2  = (const float*)d_in[3];
    const float* b2  = (const float*)d_in[4];
    const float* w3  = (const float*)d_in[5];
    const float* b3  = (const float*)d_in[6];
    const float* wf  = (const float*)d_in[7];
    const float* bf  = (const float*)d_in[8];
    const float* qw  = (const float*)d_in[9];
    const float* wc1 = (const float*)d_in[10];
    const float* bc1 = (const float*)d_in[11];
    const float* wc2 = (const float*)d_in[12];
    const float* bc2 = (const float*)d_in[13];
    const float* wc3 = (const float*)d_in[14];
    const float* bc3 = (const float*)d_in[15];
    const float* wc4 = (const float*)d_in[16];
    const float* bc4 = (const float*)d_in[17];
    const float* wc5 = (const float*)d_in[18];
    const float* bc5 = (const float*)d_in[19];
    float* out = (float*)d_out;

    float* poolbuf = (float*)d_ws;   // 4096*64 floats = 1 MB

    convpool_kernel<<<4096, 256, 0, stream>>>(x, w1, b1, w2, b2, w3, b3, poolbuf);
    head_kernel<<<1024, 256, 0, stream>>>(poolbuf, wf, bf, qw,
                                          wc1, bc1, wc2, bc2, wc3, bc3,
                                          wc4, bc4, wc5, bc5, out);
}